// Round 4
// baseline (221.971 us; speedup 1.0000x reference)
//
#include <hip/hip_runtime.h>
#include <hip/hip_bf16.h>
#include <stdint.h>

// Problem constants
#define NFEAT 4096   // IN_FEATURES == OUT_FEATURES
#define MROWS 1024   // batch
// K (top-k) = 41, ALPHA_LR = 0.01, NUM_DYKSTRA_ITER = 50

typedef __bf16 bf16x8 __attribute__((ext_vector_type(8)));
typedef float  f32x4  __attribute__((ext_vector_type(4)));

__device__ __forceinline__ unsigned short bf16_rne(float f) {
    unsigned int u = __float_as_uint(f);
    unsigned int r = (u + 0x7fffu + ((u >> 16) & 1u)) >> 16;
    return (unsigned short)r;
}

#define GLDS(src, dst) \
    __builtin_amdgcn_global_load_lds((__attribute__((address_space(1))) const void*)(src), \
                                     (__attribute__((address_space(3))) void*)(dst), 16, 0, 0)

// ---------------- Kernel 1: Dykstra soft top-k (1 block) ----------------
__global__ __launch_bounds__(256) void dykstra_kernel(const float* __restrict__ alpha,
                                                      float* __restrict__ g) {
    __shared__ float red[8];
    const int tid = threadIdx.x;
    float y[16], p[16], q[16], yp[16];
    #pragma unroll
    for (int j = 0; j < 16; ++j) {
        y[j] = alpha[tid + 256 * j] / 0.01f;   // y0 = x / l
        p[j] = 0.0f;
        q[j] = 0.0f;
    }
    for (int it = 0; it < 50; ++it) {
        float s = 0.0f;
        #pragma unroll
        for (int j = 0; j < 16; ++j) { yp[j] = y[j] + p[j]; s += yp[j]; }
        #pragma unroll
        for (int off = 32; off > 0; off >>= 1) s += __shfl_down(s, off, 64);
        const int half = (it & 1) * 4;          // WAR-safe double buffer
        if ((tid & 63) == 0) red[half + (tid >> 6)] = s;
        __syncthreads();
        const float S = (red[half] + red[half + 1]) + (red[half + 2] + red[half + 3]);
        const float shift = (S - 41.0f) / 4096.0f;  // (sum - k) / n
        #pragma unroll
        for (int j = 0; j < 16; ++j) {
            float y_hp = yp[j] - shift;
            p[j] = yp[j] - y_hp;            // NOT folded to 'shift' (fp semantics)
            float yq = y_hp + q[j];
            float yb = fminf(fmaxf(yq, 0.0f), 1.0f);
            q[j] = yq - yb;
            y[j] = yb;
        }
    }
    #pragma unroll
    for (int j = 0; j < 16; ++j) g[tid + 256 * j] = y[j];
}

// ---------------- Kernel 2: cvt x->bf16 + materialize W in bf16 -------------
// Each of 1024 blocks first converts its 16 KB slice of x, then builds a
// 256(r) x 64(c) tile of W[r,c] = g[(r-c)%n] * V[(r-c)%n, c].
// LDS band stride padded to 66 elems: write-phase anti-diagonal reads were
// 4-way bank-conflicted at stride 64 (drb step === 0 mod 32); at 66 they are
// <=2-way (free, m136).
__global__ __launch_bounds__(256) void build_w_kernel(const float* __restrict__ V,
                                                      const float* __restrict__ g,
                                                      const float* __restrict__ x,
                                                      unsigned short* __restrict__ xb,
                                                      unsigned short* __restrict__ Wb) {
    __shared__ unsigned short vb[319 * 66];   // ~42 KB bf16, already *g
    const int tid = threadIdx.x;
    const int bid = blockIdx.y * 64 + blockIdx.x;
    // --- cvt slice: 4096 floats per block ---
    {
        const size_t base = (size_t)bid * 4096 + (size_t)tid * 16;
        float4 a0 = *(const float4*)(x + base);
        float4 a1 = *(const float4*)(x + base + 4);
        float4 a2 = *(const float4*)(x + base + 8);
        float4 a3 = *(const float4*)(x + base + 12);
        uint4 s0, s1;
        s0.x = bf16_rne(a0.x) | ((unsigned)bf16_rne(a0.y) << 16);
        s0.y = bf16_rne(a0.z) | ((unsigned)bf16_rne(a0.w) << 16);
        s0.z = bf16_rne(a1.x) | ((unsigned)bf16_rne(a1.y) << 16);
        s0.w = bf16_rne(a1.z) | ((unsigned)bf16_rne(a1.w) << 16);
        s1.x = bf16_rne(a2.x) | ((unsigned)bf16_rne(a2.y) << 16);
        s1.y = bf16_rne(a2.z) | ((unsigned)bf16_rne(a2.w) << 16);
        s1.z = bf16_rne(a3.x) | ((unsigned)bf16_rne(a3.y) << 16);
        s1.w = bf16_rne(a3.z) | ((unsigned)bf16_rne(a3.w) << 16);
        *(uint4*)(xb + base)     = s0;
        *(uint4*)(xb + base + 8) = s1;
    }
    // --- band load: 319 rows x 16 float4, premultiplied by g ---
    const int c0 = blockIdx.x * 64;
    const int r0 = blockIdx.y * 256;
    const int i0 = (r0 - c0 - 63) & 4095;
    #pragma unroll
    for (int j = 0; j < 20; ++j) {
        int idx = tid + 256 * j;
        if (idx < 5104) {
            int t   = idx >> 4;
            int col = (idx & 15) << 2;
            int i   = (i0 + t) & 4095;
            float gv = g[i];
            float4 v = *(const float4*)(V + (size_t)i * NFEAT + c0 + col);
            uint2 pk;
            pk.x = bf16_rne(v.x * gv) | ((unsigned)bf16_rne(v.y * gv) << 16);
            pk.y = bf16_rne(v.z * gv) | ((unsigned)bf16_rne(v.w * gv) << 16);
            *(uint2*)(vb + t * 66 + col) = pk;
        }
    }
    __syncthreads();
    const int dcp = tid & 15;       // col group: cols 4*dcp .. 4*dcp+3
    const int drb = tid >> 4;       // 16 rows per pass
    #pragma unroll
    for (int j = 0; j < 16; ++j) {
        int dr = drb + 16 * j;
        int c  = dcp * 4;
        int tb = dr - c + 63;       // in [3, 318]
        unsigned short w0 = vb[tb * 66 + c];
        unsigned short w1 = vb[(tb - 1) * 66 + c + 1];
        unsigned short w2 = vb[(tb - 2) * 66 + c + 2];
        unsigned short w3 = vb[(tb - 3) * 66 + c + 3];
        uint2 st;
        st.x = w0 | ((unsigned)w1 << 16);
        st.y = w2 | ((unsigned)w3 << 16);
        *(uint2*)(Wb + (size_t)(r0 + dr) * NFEAT + c0 + c) = st;
    }
}

// ---------------- Kernel 3: split-K GEMM, 128x256x32, 2 blocks/CU ----------
// v5: REGIME change. v3/v4 (1 block/CU, barrier-phased 256^2) plateaued at
// 62us / MfmaUtil 21%: per-K-step floors are ~1024cyc (MFMA pipe) and
// ~1400cyc (LDS pipe) but measured 4650cyc -- lockstep barriers leave both
// pipes idle with nothing co-resident to fill the bubbles (m233). m103/m114:
// independent co-resident blocks overlap MFMA and LDS/stage pipes
// automatically (912 TF with a SIMPLE loop at 3 blocks/CU).
// Geometry: tile 128(M)x256(N), 256 thr = 4 waves (2Mx2N), per-wave 64x128
// (12 ds_read per 32 MFMA -- read-efficient). BK=32, NBUF=3 -> LDS 72 KB ->
// exactly 2 blocks/CU (144 KB, 8 waves/CU). Grid (16,8,4) = 512 blocks.
// Co-resident pairs (z, z+2) share n0 -> same B slab, L2-local; same-n0
// blocks still one XCD (16 = 0 mod 8, 128 = 0 mod 8).
// Pipeline: depth-2 prefetch, per K-step: {vmcnt(6); s_barrier; fence;
// stage(kt+2); compute(kt)}. 6 GLDS/thread/tile -> vmcnt(6) retires exactly
// tile kt, keeps 6 in flight (never 0 until last iter).
// WAR: a wave past barrier(kt+1) stages buf[(kt+3)%3] == buf[kt%3], but it
//   only passes that barrier after ALL waves finished compute(kt) (their
//   ds_reads are lgkm-drained into regs before their MFMAs, which precede
//   the barrier). Skew is bounded by the barrier itself.
// RAW: every wave's own vmcnt(6) (tile kt retired) precedes barrier(kt);
//   all waves past barrier(kt) => tile kt fully in LDS.
// Compiler keeps its fine-grained lgkmcnt scheduling (no asm lgkm /
// sched_barrier / setprio -- m97/m141/m190). asm ""::: "memory" fences pin
// GLDS and ds_read on the correct side of each barrier.
__global__ __launch_bounds__(256, 2) void gemm_kernel(const unsigned short* __restrict__ A,
                                                      const unsigned short* __restrict__ B,
                                                      float* __restrict__ C0,
                                                      float* __restrict__ Cp) {
    __shared__ unsigned short As[3][4096];   // [kg4][row128][8] per buf, 8 KB
    __shared__ unsigned short Bs[3][8192];   // [kg4][row256][8] per buf, 16 KB
    const int tid  = threadIdx.x;
    const int lane = tid & 63;
    const int w    = tid >> 6;       // 0..3
    const int wm   = w & 1;          // m strip (64 rows)
    const int wn   = w >> 1;         // n strip (128 cols)
    const int m0   = blockIdx.y * 128;
    const int n0   = blockIdx.x * 256;
    const int kbase = blockIdx.z * 1024;   // 32 K-steps x BK=32

    f32x4 acc[4][8];
    #pragma unroll
    for (int i = 0; i < 4; ++i)
        #pragma unroll
        for (int j = 0; j < 8; ++j)
            acc[i][j] = (f32x4){0.f, 0.f, 0.f, 0.f};

    // staging: wave w stages k-group kg=w for both A (2 GLDS) and B (4 GLDS)
    const unsigned short* aS = A + (size_t)(m0 + lane) * NFEAT + kbase + w * 8;
    const unsigned short* bS = B + (size_t)(n0 + lane) * NFEAT + kbase + w * 8;
    const int aD = w * 1024;   // wave-uniform LDS base (elems); HW adds lane*8
    const int bD = w * 2048;

    auto stage = [&](int kt, int nb) {
        const int ko = kt * 32;
        GLDS(aS + ko,               As[nb] + aD);
        GLDS(aS + ko + 64 * NFEAT,  As[nb] + aD + 512);
        GLDS(bS + ko,               Bs[nb] + bD);
        GLDS(bS + ko + 64 * NFEAT,  Bs[nb] + bD + 512);
        GLDS(bS + ko + 128 * NFEAT, Bs[nb] + bD + 1024);
        GLDS(bS + ko + 192 * NFEAT, Bs[nb] + bD + 1536);
    };

    const int kg4 = lane >> 4;
    const int lm  = lane & 15;
    const int aOff = kg4 * 1024 + (wm * 64 + lm) * 8;
    const int bOff = kg4 * 2048 + (wn * 128 + lm) * 8;

    auto compute = [&](int cur) {
        const unsigned short* aRd = As[cur] + aOff;
        const unsigned short* bRd = Bs[cur] + bOff;
        bf16x8 af[4], bfv[8];
        #pragma unroll
        for (int mi = 0; mi < 4; ++mi) af[mi]  = *(const bf16x8*)(aRd + mi * 128);
        #pragma unroll
        for (int ni = 0; ni < 8; ++ni) bfv[ni] = *(const bf16x8*)(bRd + ni * 128);
        #pragma unroll
        for (int mi = 0; mi < 4; ++mi)
            #pragma unroll
            for (int ni = 0; ni < 8; ++ni)
                acc[mi][ni] = __builtin_amdgcn_mfma_f32_16x16x32_bf16(af[mi], bfv[ni],
                                                                      acc[mi][ni], 0, 0, 0);
    };

#define GITER(KT, CUR, SB) do {                                   \
    asm volatile("s_waitcnt vmcnt(6)" ::: "memory");              \
    __builtin_amdgcn_s_barrier();                                 \
    asm volatile("" ::: "memory");                                \
    stage((KT) + 2, SB);                                          \
    compute(CUR);                                                 \
} while (0)

    stage(0, 0); stage(1, 1);              // prologue: 12 loads in flight
    #pragma unroll 1
    for (int kt0 = 0; kt0 < 30; kt0 += 3) {
        GITER(kt0,     0, 2);
        GITER(kt0 + 1, 1, 0);
        GITER(kt0 + 2, 2, 1);
    }
    // kt=30 (buf 0): outstanding {30,31}=12 -> vmcnt(6) retires tile 30
    asm volatile("s_waitcnt vmcnt(6)" ::: "memory");
    __builtin_amdgcn_s_barrier();
    asm volatile("" ::: "memory");
    compute(0);
    // kt=31 (buf 1): outstanding {31}=6 -> vmcnt(0)
    asm volatile("s_waitcnt vmcnt(0)" ::: "memory");
    __builtin_amdgcn_s_barrier();
    asm volatile("" ::: "memory");
    compute(1);
#undef GITER

    float* Cz = (blockIdx.z == 0) ? C0 : (Cp + (size_t)(blockIdx.z - 1) * MROWS * NFEAT);
    // C/D layout: col = lane&15, row = (lane>>4)*4 + reg  (m89-verified)
    const int crow = m0 + wm * 64 + (lane >> 4) * 4;
    const int ccol = n0 + wn * 128 + lm;
    #pragma unroll
    for (int mi = 0; mi < 4; ++mi)
        #pragma unroll
        for (int ni = 0; ni < 8; ++ni) {
            float* cp = Cz + (size_t)(crow + mi * 16) * NFEAT + ccol + ni * 16;
            #pragma unroll
            for (int r = 0; r < 4; ++r)
                cp[(size_t)r * NFEAT] = acc[mi][ni][r];
        }
}

// ---------------- Kernel 4: split-K reduce: out += sum of partials ----------
__global__ __launch_bounds__(256) void reduce_kernel(float* __restrict__ out,
                                                     const float* __restrict__ Cp) {
    const size_t i = (size_t)(blockIdx.x * 256 + threadIdx.x) * 4;
    float4 a = *(const float4*)(out + i);
    #pragma unroll
    for (int s = 0; s < 3; ++s) {
        float4 b = *(const float4*)(Cp + (size_t)s * MROWS * NFEAT + i);
        a.x += b.x; a.y += b.y; a.z += b.z; a.w += b.w;
    }
    *(float4*)(out + i) = a;
}

extern "C" void kernel_launch(void* const* d_in, const int* in_sizes, int n_in,
                              void* d_out, int out_size, void* d_ws, size_t ws_size,
                              hipStream_t stream) {
    const float* x     = (const float*)d_in[0];   // (1024, 4096) fp32
    const float* V     = (const float*)d_in[1];   // (4096, 4096) fp32
    const float* alpha = (const float*)d_in[2];   // (4096,) fp32
    float* out = (float*)d_out;                   // (1024, 4096) fp32

    char* ws = (char*)d_ws;
    const size_t xb_off = 16384;
    const size_t wb_off = xb_off + (size_t)MROWS * NFEAT * 2;   // + 8 MB
    const size_t cp_off = wb_off + (size_t)NFEAT * NFEAT * 2;   // +32 MB
    float* g           = (float*)ws;
    unsigned short* xb = (unsigned short*)(ws + xb_off);
    unsigned short* Wb = (unsigned short*)(ws + wb_off);
    float* Cp          = (float*)(ws + cp_off);                 // 48 MB (S=4)
    // ws_size >= 152 MB confirmed empirically (r5 ran S=8 = cp_off + 112 MB).

    hipLaunchKernelGGL(dykstra_kernel, dim3(1),        dim3(256), 0, stream, alpha, g);
    hipLaunchKernelGGL(build_w_kernel, dim3(64, 16),   dim3(256), 0, stream, V, g, x, xb, Wb);
    hipLaunchKernelGGL(gemm_kernel,    dim3(16, 8, 4), dim3(256), 0, stream, xb, Wb, out, Cp);
    hipLaunchKernelGGL(reduce_kernel,  dim3(MROWS * NFEAT / (256 * 4)), dim3(256), 0, stream,
                       out, Cp);
}